// Round 5
// baseline (131.300 us; speedup 1.0000x reference)
//
#include <hip/hip_runtime.h>
#include <hip/hip_bf16.h>

// Switch MoE (top-1), B=2 S=1024 H=768 F=3072 E=8 on MI355X.
// Outputs concat in d_out: next_states[2048*768] f32, router_logits[2048*8] f32,
// expert_index[2048] written as float values.

#define T_TOKENS 2048
#define H_DIM 768
#define F_DIM 3072
#define E_NUM 8
#define MSLOTS1 40  // 64-row tiles: sum ceil(cnt/64) < 32+8, padded
#define MSLOTS2 72  // 32-row tiles: sum ceil(cnt/32) < 64+8, padded

typedef __attribute__((ext_vector_type(8))) short bf16x8;
typedef __attribute__((ext_vector_type(4))) float f32x4;

__device__ inline unsigned short f2bf(float f) {
  __hip_bfloat16 b = __float2bfloat16(f);
  return *reinterpret_cast<unsigned short*>(&b);
}
__device__ inline unsigned int pack2(float lo, float hi) {
  return (unsigned int)f2bf(lo) | ((unsigned int)f2bf(hi) << 16);
}

// ---------------- Router: one wave per token ----------------
__global__ void router_kernel(const float* __restrict__ X, const float* __restrict__ Wr,
                              float* __restrict__ logits, float* __restrict__ idx_out,
                              int* __restrict__ expert, float* __restrict__ prob,
                              int* __restrict__ counts) {
  int wave = threadIdx.x >> 6, lane = threadIdx.x & 63;
  int t = blockIdx.x * 4 + wave;
  if (t >= T_TOKENS) return;
  const float* x = X + (size_t)t * H_DIM;
  float acc[E_NUM];
#pragma unroll
  for (int e = 0; e < E_NUM; ++e) acc[e] = 0.f;
  int h0 = lane * 12;
#pragma unroll
  for (int j = 0; j < 12; ++j) {
    float xv = x[h0 + j];
    const float4* wr = reinterpret_cast<const float4*>(Wr + (size_t)(h0 + j) * E_NUM);
    float4 w0 = wr[0], w1 = wr[1];
    acc[0] += xv * w0.x; acc[1] += xv * w0.y; acc[2] += xv * w0.z; acc[3] += xv * w0.w;
    acc[4] += xv * w1.x; acc[5] += xv * w1.y; acc[6] += xv * w1.z; acc[7] += xv * w1.w;
  }
#pragma unroll
  for (int e = 0; e < E_NUM; ++e) {
#pragma unroll
    for (int s = 32; s > 0; s >>= 1) acc[e] += __shfl_down(acc[e], s);
  }
  if (lane == 0) {
    float m = acc[0]; int am = 0;
#pragma unroll
    for (int e = 1; e < E_NUM; ++e) {
      if (acc[e] > m) { m = acc[e]; am = e; }  // strict > == jnp.argmax first-occurrence
    }
    float sum = 0.f;
#pragma unroll
    for (int e = 0; e < E_NUM; ++e) sum += __expf(acc[e] - m);
    float p = 1.f / sum;
#pragma unroll
    for (int e = 0; e < E_NUM; ++e) logits[(size_t)t * E_NUM + e] = acc[e];
    idx_out[t] = (float)am;
    expert[t] = am;
    prob[t] = p;
    atomicAdd(&counts[am], 1);
  }
}

// ------- Fused scan + scatter + slot tables (one block) -------
__global__ void scan_scatter_kernel(const int* __restrict__ counts,
                                    const int* __restrict__ expert,
                                    int* __restrict__ offs, int* __restrict__ perm,
                                    int* __restrict__ mse1, int* __restrict__ msm1,
                                    int* __restrict__ mse2, int* __restrict__ msm2) {
  __shared__ int so[E_NUM + 1];
  __shared__ int cur[E_NUM];
  int tid = threadIdx.x;
  if (tid == 0) {
    int s = 0;
    for (int e = 0; e < E_NUM; ++e) { so[e] = s; s += counts[e]; }
    so[E_NUM] = s;
    int n1 = 0, n2 = 0;
    for (int e = 0; e < E_NUM; ++e) {
      for (int m0 = 0; m0 < counts[e]; m0 += 64) { mse1[n1] = e; msm1[n1] = m0; ++n1; }
      for (int m0 = 0; m0 < counts[e]; m0 += 32) { mse2[n2] = e; msm2[n2] = m0; ++n2; }
    }
    for (; n1 < MSLOTS1; ++n1) { mse1[n1] = -1; msm1[n1] = 0; }
    for (; n2 < MSLOTS2; ++n2) { mse2[n2] = -1; msm2[n2] = 0; }
  }
  if (tid < E_NUM) cur[tid] = 0;
  __syncthreads();
  if (tid < E_NUM + 1) offs[tid] = so[tid];
  for (int i = tid; i < T_TOKENS; i += blockDim.x) {
    int e = expert[i];
    int pos = atomicAdd(&cur[e], 1);
    perm[so[e] + pos] = i;
  }
}

// ---------------- Gather X rows -> contiguous bf16 ----------------
__global__ void gather_kernel(const float* __restrict__ X, const int* __restrict__ perm,
                              __hip_bfloat16* __restrict__ xg) {
  int wave = threadIdx.x >> 6, lane = threadIdx.x & 63;
  int g = blockIdx.x * 4 + wave;
  if (g >= T_TOKENS) return;
  int token = perm[g];
  const float4* src = reinterpret_cast<const float4*>(X + (size_t)token * H_DIM + lane * 12);
  __hip_bfloat16* dst = xg + (size_t)g * H_DIM + lane * 12;
#pragma unroll
  for (int i = 0; i < 3; ++i) {
    float4 v = src[i];
    ushort4 u;
    u.x = f2bf(v.x); u.y = f2bf(v.y); u.z = f2bf(v.z); u.w = f2bf(v.w);
    *reinterpret_cast<ushort4*>(dst + i * 4) = u;
  }
}

// ---------------- Grouped GEMM, depth-3 pipelined ----------------
// C[m,n] = sum_k A[m,k] * W[e][k,n]. BN=128, BK=64. T=512: BM=64, 8 waves
// (4m x 2n); T=256: BM=32, 4 waves (2m x 2n). Wavetile 16x64.
// 3 LDS buffers, prefetch 3 tiles ahead, counted vmcnt (no vmcnt(0) drain).
// LDS rows 128B = 8 x 16B slots, slot' = slot ^ (row&7) (conflict-free).
// B (f32 [K][N]) loaded as float4 (4n x 4k or 4n x 8k per thread), packed
// in-register to bf16 k-pairs, written b64/b128.
template <int RELU, int K, int N, int T, int MS>
__global__ __launch_bounds__(T, T == 512 ? 4 : 2) void moe_gemm(
    const __hip_bfloat16* __restrict__ A, const float* __restrict__ Wt,
    __hip_bfloat16* __restrict__ Cbf, float* __restrict__ Cf,
    const int* __restrict__ offs, const int* __restrict__ perm,
    const float* __restrict__ prob, const int* __restrict__ mse,
    const int* __restrict__ msm0) {
  constexpr int BM = (T == 512) ? 64 : 32;
  constexpr int ABUF = BM * 128;           // bytes
  constexpr int BBUF = 128 * 128;
  constexpr int BUFSZ = ABUF + BBUF;
  constexpr int nt = K / 64;
  constexpr int RPT = (T == 512) ? 4 : 8;  // B k-rows per thread
  __shared__ __align__(16) char lds[3 * BUFSZ];

  // ---- work decode with XCD-chunk swizzle ----
  const int nw = gridDim.x;                // multiple of 8
  const int cpx = nw >> 3;
  const int d = blockIdx.x;
  const int w = (d & 7) * cpx + (d >> 3);  // consecutive w -> same XCD
  const int nt_i = w / MS, slot = w - nt_i * MS;
  const int e = mse[slot];
  if (e < 0) return;
  const int base = offs[e], cnt = offs[e + 1] - base;
  const int m0 = msm0[slot];
  const int rows = min(BM, cnt - m0);
  const int n0 = nt_i * 128;

  const int tid = threadIdx.x;
  const int lane = tid & 63, wv = tid >> 6;
  const int wr = wv >> 1, wc = wv & 1;
  const int lr = lane & 15, lg = lane >> 4;

  // ---- A staging: thread -> (row, 16B k-slot) ----
  const int m_a = tid >> 3, sl_a = tid & 7;
  const __hip_bfloat16* Ap = A + (size_t)(base + m0 + min(m_a, rows - 1)) * K + sl_a * 8;
  const int a_woff = m_a * 128 + ((sl_a ^ (m_a & 7)) << 4);

  // ---- B staging: thread -> (4 n-cols, RPT k-rows), float4 loads ----
  const int n4 = (tid & 31) * 4;
  const int kq = (tid >> 5) * RPT;
  const float* Bp = Wt + (size_t)e * K * N + (size_t)kq * N + n0 + n4;

  // ---- fragment LDS offsets ----
  const int ar = wr * 16 + lr;
  int aof[2], bof[2][4];
#pragma unroll
  for (int ks = 0; ks < 2; ++ks) {
    aof[ks] = ar * 128 + (((ks * 4 + lg) ^ (ar & 7)) << 4);
#pragma unroll
    for (int ni = 0; ni < 4; ++ni) {
      int br = wc * 64 + ni * 16 + lr;
      bof[ks][ni] = ABUF + br * 128 + (((ks * 4 + lg) ^ (br & 7)) << 4);
    }
  }

  f32x4 acc[4];
#pragma unroll
  for (int i = 0; i < 4; ++i) acc[i] = (f32x4){0.f, 0.f, 0.f, 0.f};

  int4 aq0, aq1;
  f32x4 bq0[RPT], bq1[RPT];

#define LOADT(RS, TT) {                                                         \
    aq##RS = *reinterpret_cast<const int4*>(Ap + (size_t)(TT) * 64);            \
    _Pragma("unroll")                                                           \
    for (int r = 0; r < RPT; ++r)                                               \
      bq##RS[r] = *reinterpret_cast<const f32x4*>(Bp + (size_t)((TT) * 64 + r) * N); \
  }

#define WRITET(BUF, RS) {                                                       \
    char* base_ = lds + (BUF) * BUFSZ;                                          \
    *reinterpret_cast<int4*>(base_ + a_woff) = aq##RS;                          \
    _Pragma("unroll")                                                           \
    for (int cc = 0; cc < 4; ++cc) {                                            \
      int row_ = n4 + cc;                                                       \
      if constexpr (T == 512) {                                                 \
        int g_ = tid >> 5; /* kq = 4g */                                        \
        int2 u_;                                                                \
        u_.x = (int)pack2(bq##RS[0][cc], bq##RS[1][cc]);                        \
        u_.y = (int)pack2(bq##RS[2][cc], bq##RS[3][cc]);                        \
        *reinterpret_cast<int2*>(base_ + ABUF + row_ * 128 +                    \
            (((g_ >> 1) ^ (row_ & 7)) << 4) + ((g_ & 1) << 3)) = u_;            \
      } else {                                                                  \
        int s_ = tid >> 5; /* kq = 8s */                                        \
        int4 u_;                                                                \
        u_.x = (int)pack2(bq##RS[0][cc], bq##RS[1][cc]);                        \
        u_.y = (int)pack2(bq##RS[2][cc], bq##RS[3][cc]);                        \
        u_.z = (int)pack2(bq##RS[4][cc], bq##RS[5][cc]);                        \
        u_.w = (int)pack2(bq##RS[6][cc], bq##RS[7][cc]);                        \
        *reinterpret_cast<int4*>(base_ + ABUF + row_ * 128 +                    \
            ((s_ ^ (row_ & 7)) << 4)) = u_;                                     \
      }                                                                         \
    }                                                                           \
  }

#define MFMA_STEP(BUF) {                                                        \
    const char* base_ = lds + (BUF) * BUFSZ;                                    \
    _Pragma("unroll")                                                           \
    for (int ks = 0; ks < 2; ++ks) {                                            \
      bf16x8 av = *reinterpret_cast<const bf16x8*>(base_ + aof[ks]);            \
      _Pragma("unroll")                                                         \
      for (int ni = 0; ni < 4; ++ni) {                                          \
        bf16x8 bv = *reinterpret_cast<const bf16x8*>(base_ + bof[ks][ni]);      \
        acc[ni] = __builtin_amdgcn_mfma_f32_16x16x32_bf16(av, bv, acc[ni], 0, 0, 0); \
      }                                                                         \
    }                                                                           \
  }

#define SYNC() {                                                                \
    asm volatile("s_waitcnt lgkmcnt(0)" ::: "memory");                          \
    __builtin_amdgcn_s_barrier();                                               \
    asm volatile("" ::: "memory");                                              \
  }

#define STEP(TT, BUF, WBUF, RS) {                                               \
    MFMA_STEP(BUF);                                                             \
    if ((TT) + 1 < nt) WRITET(WBUF, RS);                                        \
    if ((TT) + 3 < nt) LOADT(RS, (TT) + 3);                                     \
    SYNC();                                                                     \
  }

  // prologue: tiles 0,1,2 in flight; tile0 written to buf0
  LOADT(0, 0);
  LOADT(1, 1);
  WRITET(0, 0);
  LOADT(0, 2);
  SYNC();

  for (int t0 = 0; t0 < nt; t0 += 6) {
    STEP(t0 + 0, 0, 1, 1);
    STEP(t0 + 1, 1, 2, 0);
    STEP(t0 + 2, 2, 0, 1);
    STEP(t0 + 3, 0, 1, 0);
    STEP(t0 + 4, 1, 2, 1);
    STEP(t0 + 5, 2, 0, 0);
  }
#undef LOADT
#undef WRITET
#undef MFMA_STEP
#undef SYNC
#undef STEP

  // ---- epilogue: C/D frag row=(lane>>4)*4+reg, col=lane&15 ----
#pragma unroll
  for (int r = 0; r < 4; ++r) {
    int row = wr * 16 + lg * 4 + r;
    if (row < rows) {
      if (RELU) {
        __hip_bfloat16* dst = Cbf + (size_t)(base + m0 + row) * N + n0 + wc * 64 + lr;
#pragma unroll
        for (int ni = 0; ni < 4; ++ni) {
          float v = acc[ni][r];
          dst[ni * 16] = __float2bfloat16(v > 0.f ? v : 0.f);
        }
      } else {
        int token = perm[base + m0 + row];
        float p = prob[token];
        float* dst = Cf + (size_t)token * N + n0 + wc * 64 + lr;
#pragma unroll
        for (int ni = 0; ni < 4; ++ni) dst[ni * 16] = acc[ni][r] * p;
      }
    }
  }
}

extern "C" void kernel_launch(void* const* d_in, const int* in_sizes, int n_in,
                              void* d_out, int out_size, void* d_ws, size_t ws_size,
                              hipStream_t stream) {
  const float* X = (const float*)d_in[0];
  const float* Wr = (const float*)d_in[1];
  const float* W1 = (const float*)d_in[2];
  const float* W2 = (const float*)d_in[3];

  float* out_states = (float*)d_out;
  float* out_logits = out_states + (size_t)T_TOKENS * H_DIM;
  float* out_index = out_logits + (size_t)T_TOKENS * E_NUM;

  char* ws = (char*)d_ws;
  int* counts = (int*)(ws + 0);        // 8 ints
  int* offs = (int*)(ws + 64);         // 9 ints
  int* expert = (int*)(ws + 128);      // 2048 ints
  float* prob = (float*)(ws + 8320);   // 2048 f32
  int* perm = (int*)(ws + 16512);      // 2048 ints
  int* mse1 = (int*)(ws + 24704);      // 40 ints
  int* msm1 = (int*)(ws + 24896);      // 40 ints
  int* mse2 = (int*)(ws + 25088);      // 72 ints
  int* msm2 = (int*)(ws + 25408);      // 72 ints
  __hip_bfloat16* xg = (__hip_bfloat16*)(ws + 25728);      // 2048*768 bf16
  __hip_bfloat16* hbuf = (__hip_bfloat16*)(ws + 3171456);  // 2048*3072 bf16

  hipMemsetAsync(d_ws, 0, 64, stream);  // zero counts

  router_kernel<<<T_TOKENS / 4, 256, 0, stream>>>(X, Wr, out_logits, out_index, expert, prob, counts);
  scan_scatter_kernel<<<1, 1024, 0, stream>>>(counts, expert, offs, perm, mse1, msm1, mse2, msm2);
  gather_kernel<<<T_TOKENS / 4, 256, 0, stream>>>(X, perm, xg);

  // h = relu(xg @ W1[e]) : K=768, N=3072 -> 24 n-tiles x 40 slots = 960 blocks
  moe_gemm<1, H_DIM, F_DIM, 512, MSLOTS1><<<(F_DIM / 128) * MSLOTS1, 512, 0, stream>>>(
      xg, W1, hbuf, nullptr, offs, nullptr, nullptr, mse1, msm1);
  // y = (h @ W2[e]) * prob, scattered : K=3072, N=768 -> 6 x 72 = 432 blocks
  moe_gemm<0, F_DIM, H_DIM, 256, MSLOTS2><<<(H_DIM / 128) * MSLOTS2, 256, 0, stream>>>(
      hbuf, W2, nullptr, out_states, offs, perm, prob, mse2, msm2);
}

// Round 6
// 123.733 us; speedup vs baseline: 1.0612x; 1.0612x over previous
//
#include <hip/hip_runtime.h>
#include <hip/hip_bf16.h>

// Switch MoE (top-1), B=2 S=1024 H=768 F=3072 E=8 on MI355X.
// Outputs concat in d_out: next_states[2048*768] f32, router_logits[2048*8] f32,
// expert_index[2048] written as float values.

#define T_TOKENS 2048
#define H_DIM 768
#define F_DIM 3072
#define E_NUM 8
#define MSLOTS1 40  // 64-row tiles: sum ceil(cnt/64) < 32+8, padded
#define MSLOTS2 72  // 32-row tiles: sum ceil(cnt/32) < 64+8, padded

typedef __attribute__((ext_vector_type(8))) short bf16x8;
typedef __attribute__((ext_vector_type(4))) float f32x4;

__device__ inline unsigned short f2bf(float f) {
  __hip_bfloat16 b = __float2bfloat16(f);
  return *reinterpret_cast<unsigned short*>(&b);
}
__device__ inline unsigned int pack2(float lo, float hi) {
  return (unsigned int)f2bf(lo) | ((unsigned int)f2bf(hi) << 16);
}

// ---------------- Router: one wave per token ----------------
__global__ void router_kernel(const float* __restrict__ X, const float* __restrict__ Wr,
                              float* __restrict__ logits, float* __restrict__ idx_out,
                              int* __restrict__ expert, float* __restrict__ prob,
                              int* __restrict__ counts) {
  int wave = threadIdx.x >> 6, lane = threadIdx.x & 63;
  int t = blockIdx.x * 4 + wave;
  if (t >= T_TOKENS) return;
  const float* x = X + (size_t)t * H_DIM;
  float acc[E_NUM];
#pragma unroll
  for (int e = 0; e < E_NUM; ++e) acc[e] = 0.f;
  int h0 = lane * 12;
#pragma unroll
  for (int j = 0; j < 12; ++j) {
    float xv = x[h0 + j];
    const float4* wr = reinterpret_cast<const float4*>(Wr + (size_t)(h0 + j) * E_NUM);
    float4 w0 = wr[0], w1 = wr[1];
    acc[0] += xv * w0.x; acc[1] += xv * w0.y; acc[2] += xv * w0.z; acc[3] += xv * w0.w;
    acc[4] += xv * w1.x; acc[5] += xv * w1.y; acc[6] += xv * w1.z; acc[7] += xv * w1.w;
  }
#pragma unroll
  for (int e = 0; e < E_NUM; ++e) {
#pragma unroll
    for (int s = 32; s > 0; s >>= 1) acc[e] += __shfl_down(acc[e], s);
  }
  if (lane == 0) {
    float m = acc[0]; int am = 0;
#pragma unroll
    for (int e = 1; e < E_NUM; ++e) {
      if (acc[e] > m) { m = acc[e]; am = e; }  // strict > == jnp.argmax first-occurrence
    }
    float sum = 0.f;
#pragma unroll
    for (int e = 0; e < E_NUM; ++e) sum += __expf(acc[e] - m);
    float p = 1.f / sum;
#pragma unroll
    for (int e = 0; e < E_NUM; ++e) logits[(size_t)t * E_NUM + e] = acc[e];
    idx_out[t] = (float)am;
    expert[t] = am;
    prob[t] = p;
    atomicAdd(&counts[am], 1);
  }
}

// ------- Fused scan + scatter + slot tables (one block) -------
__global__ void scan_scatter_kernel(const int* __restrict__ counts,
                                    const int* __restrict__ expert,
                                    int* __restrict__ offs, int* __restrict__ perm,
                                    int* __restrict__ mse1, int* __restrict__ msm1,
                                    int* __restrict__ mse2, int* __restrict__ msm2) {
  __shared__ int so[E_NUM + 1];
  __shared__ int cur[E_NUM];
  int tid = threadIdx.x;
  if (tid == 0) {
    int s = 0;
    for (int e = 0; e < E_NUM; ++e) { so[e] = s; s += counts[e]; }
    so[E_NUM] = s;
    int n1 = 0, n2 = 0;
    for (int e = 0; e < E_NUM; ++e) {
      for (int m0 = 0; m0 < counts[e]; m0 += 64) { mse1[n1] = e; msm1[n1] = m0; ++n1; }
      for (int m0 = 0; m0 < counts[e]; m0 += 32) { mse2[n2] = e; msm2[n2] = m0; ++n2; }
    }
    for (; n1 < MSLOTS1; ++n1) { mse1[n1] = -1; msm1[n1] = 0; }
    for (; n2 < MSLOTS2; ++n2) { mse2[n2] = -1; msm2[n2] = 0; }
  }
  if (tid < E_NUM) cur[tid] = 0;
  __syncthreads();
  if (tid < E_NUM + 1) offs[tid] = so[tid];
  for (int i = tid; i < T_TOKENS; i += blockDim.x) {
    int e = expert[i];
    int pos = atomicAdd(&cur[e], 1);
    perm[so[e] + pos] = i;
  }
}

// ---------------- Gather X rows -> contiguous bf16 ----------------
__global__ void gather_kernel(const float* __restrict__ X, const int* __restrict__ perm,
                              __hip_bfloat16* __restrict__ xg) {
  int wave = threadIdx.x >> 6, lane = threadIdx.x & 63;
  int g = blockIdx.x * 4 + wave;
  if (g >= T_TOKENS) return;
  int token = perm[g];
  const float4* src = reinterpret_cast<const float4*>(X + (size_t)token * H_DIM + lane * 12);
  __hip_bfloat16* dst = xg + (size_t)g * H_DIM + lane * 12;
#pragma unroll
  for (int i = 0; i < 3; ++i) {
    float4 v = src[i];
    ushort4 u;
    u.x = f2bf(v.x); u.y = f2bf(v.y); u.z = f2bf(v.z); u.w = f2bf(v.w);
    *reinterpret_cast<ushort4*>(dst + i * 4) = u;
  }
}

// ---------------- Grouped GEMM, depth-3 pipelined, branch-free ----------------
// C[m,n] = sum_k A[m,k] * W[e][k,n]. BN=128, BK=64. T=512: BM=64, 8 waves
// (4m x 2n); T=256: BM=32, 4 waves (2m x 2n). Wavetile 16x64.
// 3 LDS buffers, prefetch 3 tiles ahead. Main loop is BRANCH-FREE so the
// compiler emits counted vmcnt (branches force conservative vmcnt(0) waits);
// the last 6-step group is peeled with literal step indices (conditions fold).
// LDS rows 128B = 8 x 16B slots. A hash: slot^(row&7). B hash:
// slot^(row&7)^((row>>3)&7) -- rows stride 4 within a wave, so (row>>3) must
// enter the hash to spread lanes over all 8 slots (verified uniform for
// b128/b64 writes and all fragment reads).
template <int RELU, int K, int N, int T, int MS>
__global__ __launch_bounds__(T, T == 512 ? 4 : 2) void moe_gemm(
    const __hip_bfloat16* __restrict__ A, const float* __restrict__ Wt,
    __hip_bfloat16* __restrict__ Cbf, float* __restrict__ Cf,
    const int* __restrict__ offs, const int* __restrict__ perm,
    const float* __restrict__ prob, const int* __restrict__ mse,
    const int* __restrict__ msm0) {
  constexpr int BM = (T == 512) ? 64 : 32;
  constexpr int ABUF = BM * 128;           // bytes
  constexpr int BBUF = 128 * 128;
  constexpr int BUFSZ = ABUF + BBUF;
  constexpr int nt = K / 64;               // 12 or 48, divisible by 6
  constexpr int RPT = (T == 512) ? 4 : 8;  // B k-rows per thread
  __shared__ __align__(16) char lds[3 * BUFSZ];

  // ---- work decode with XCD-chunk swizzle ----
  const int nw = gridDim.x;                // multiple of 8
  const int cpx = nw >> 3;
  const int d = blockIdx.x;
  const int w = (d & 7) * cpx + (d >> 3);  // consecutive w -> same XCD
  const int nt_i = w / MS, slot = w - nt_i * MS;
  const int e = mse[slot];
  if (e < 0) return;
  const int base = offs[e], cnt = offs[e + 1] - base;
  const int m0 = msm0[slot];
  const int rows = min(BM, cnt - m0);
  const int n0 = nt_i * 128;

  const int tid = threadIdx.x;
  const int lane = tid & 63, wv = tid >> 6;
  const int wr = wv >> 1, wc = wv & 1;
  const int lr = lane & 15, lg = lane >> 4;

  // ---- A staging: thread -> (row, 16B k-slot) ----
  const int m_a = tid >> 3, sl_a = tid & 7;
  const __hip_bfloat16* Ap = A + (size_t)(base + m0 + min(m_a, rows - 1)) * K + sl_a * 8;
  const int a_woff = m_a * 128 + ((sl_a ^ (m_a & 7)) << 4);

  // ---- B staging: thread -> (4 n-cols, RPT k-rows), float4 loads ----
  const int n4 = (tid & 31) * 4;
  const int kq = (tid >> 5) * RPT;
  const float* Bp = Wt + (size_t)e * K * N + (size_t)kq * N + n0 + n4;
  // B write offsets for the 4 n-rows (cc = 0..3), conflict-free hash
  int b_woff[4];
#pragma unroll
  for (int cc = 0; cc < 4; ++cc) {
    int row_ = n4 + cc;
    int h_ = (row_ & 7) ^ ((row_ >> 3) & 7);
    if constexpr (T == 512) {
      int g_ = tid >> 5;  // kq = 4*g_: 8B sub-slot
      b_woff[cc] = ABUF + row_ * 128 + (((g_ >> 1) ^ h_) << 4) + ((g_ & 1) << 3);
    } else {
      int s_ = tid >> 5;  // kq = 8*s_: full 16B slot
      b_woff[cc] = ABUF + row_ * 128 + ((s_ ^ h_) << 4);
    }
  }

  // ---- fragment LDS offsets (A: slot^(row&7); B: +((row>>3)&7)) ----
  const int ar = wr * 16 + lr;
  int aof[2], bof[2][4];
#pragma unroll
  for (int ks = 0; ks < 2; ++ks) {
    aof[ks] = ar * 128 + (((ks * 4 + lg) ^ (ar & 7)) << 4);
#pragma unroll
    for (int ni = 0; ni < 4; ++ni) {
      int br = wc * 64 + ni * 16 + lr;
      bof[ks][ni] = ABUF + br * 128 +
                    (((ks * 4 + lg) ^ (br & 7) ^ ((br >> 3) & 7)) << 4);
    }
  }

  f32x4 acc[4];
#pragma unroll
  for (int i = 0; i < 4; ++i) acc[i] = (f32x4){0.f, 0.f, 0.f, 0.f};

  int4 aq0, aq1;
  f32x4 bq0[RPT], bq1[RPT];

#define LOADT(RS, TT) {                                                         \
    aq##RS = *reinterpret_cast<const int4*>(Ap + (size_t)(TT) * 64);            \
    _Pragma("unroll")                                                           \
    for (int r = 0; r < RPT; ++r)                                               \
      bq##RS[r] = *reinterpret_cast<const f32x4*>(Bp + (size_t)((TT) * 64 + r) * N); \
  }

#define WRITET(BUF, RS) {                                                       \
    char* base_ = lds + (BUF) * BUFSZ;                                          \
    *reinterpret_cast<int4*>(base_ + a_woff) = aq##RS;                          \
    _Pragma("unroll")                                                           \
    for (int cc = 0; cc < 4; ++cc) {                                            \
      if constexpr (T == 512) {                                                 \
        int2 u_;                                                                \
        u_.x = (int)pack2(bq##RS[0][cc], bq##RS[1][cc]);                        \
        u_.y = (int)pack2(bq##RS[2][cc], bq##RS[3][cc]);                        \
        *reinterpret_cast<int2*>(base_ + b_woff[cc]) = u_;                      \
      } else {                                                                  \
        int4 u_;                                                                \
        u_.x = (int)pack2(bq##RS[0][cc], bq##RS[1][cc]);                        \
        u_.y = (int)pack2(bq##RS[2][cc], bq##RS[3][cc]);                        \
        u_.z = (int)pack2(bq##RS[4][cc], bq##RS[5][cc]);                        \
        u_.w = (int)pack2(bq##RS[6][cc], bq##RS[7][cc]);                        \
        *reinterpret_cast<int4*>(base_ + b_woff[cc]) = u_;                      \
      }                                                                         \
    }                                                                           \
  }

#define MFMA_STEP(BUF) {                                                        \
    const char* base_ = lds + (BUF) * BUFSZ;                                    \
    _Pragma("unroll")                                                           \
    for (int ks = 0; ks < 2; ++ks) {                                            \
      bf16x8 av = *reinterpret_cast<const bf16x8*>(base_ + aof[ks]);            \
      _Pragma("unroll")                                                         \
      for (int ni = 0; ni < 4; ++ni) {                                          \
        bf16x8 bv = *reinterpret_cast<const bf16x8*>(base_ + bof[ks][ni]);      \
        acc[ni] = __builtin_amdgcn_mfma_f32_16x16x32_bf16(av, bv, acc[ni], 0, 0, 0); \
      }                                                                         \
    }                                                                           \
  }

#define SYNC() {                                                                \
    asm volatile("s_waitcnt lgkmcnt(0)" ::: "memory");                          \
    __builtin_amdgcn_s_barrier();                                               \
    asm volatile("" ::: "memory");                                              \
  }

  // branch-free step (main loop): always write next tile + load tile TT+3
#define STEP_F(TT, BUF, WBUF, RS) {                                             \
    MFMA_STEP(BUF);                                                             \
    WRITET(WBUF, RS);                                                           \
    LOADT(RS, (TT) + 3);                                                        \
    SYNC();                                                                     \
  }
  // epilogue step: TT is a LITERAL (nt-6..nt-1) -> conditions constant-fold
#define STEP_E(TT, BUF, WBUF, RS) {                                             \
    MFMA_STEP(BUF);                                                             \
    if ((TT) + 1 < nt) WRITET(WBUF, RS);                                        \
    if ((TT) + 3 < nt) LOADT(RS, (TT) + 3);                                     \
    SYNC();                                                                     \
  }

  // prologue: tiles 0,1,2 in flight; tile0 written to buf0
  LOADT(0, 0);
  LOADT(1, 1);
  WRITET(0, 0);   // counted vmcnt: tile-1 loads stay outstanding
  LOADT(0, 2);
  SYNC();

  // main loop: all steps unconditional (t0 <= nt-12 => t0+5+3 < nt)
  for (int t0 = 0; t0 + 12 <= nt; t0 += 6) {
    STEP_F(t0 + 0, 0, 1, 1);
    STEP_F(t0 + 1, 1, 2, 0);
    STEP_F(t0 + 2, 2, 0, 1);
    STEP_F(t0 + 3, 0, 1, 0);
    STEP_F(t0 + 4, 1, 2, 1);
    STEP_F(t0 + 5, 2, 0, 0);
  }
  // peeled last group (literal indices; same buffer/regset rotation)
  STEP_E(nt - 6, 0, 1, 1);
  STEP_E(nt - 5, 1, 2, 0);
  STEP_E(nt - 4, 2, 0, 1);
  STEP_E(nt - 3, 0, 1, 0);
  STEP_E(nt - 2, 1, 2, 1);
  STEP_E(nt - 1, 2, 0, 0);
#undef LOADT
#undef WRITET
#undef MFMA_STEP
#undef SYNC
#undef STEP_F
#undef STEP_E

  // ---- epilogue: C/D frag row=(lane>>4)*4+reg, col=lane&15 ----
#pragma unroll
  for (int r = 0; r < 4; ++r) {
    int row = wr * 16 + lg * 4 + r;
    if (row < rows) {
      if (RELU) {
        __hip_bfloat16* dst = Cbf + (size_t)(base + m0 + row) * N + n0 + wc * 64 + lr;
#pragma unroll
        for (int ni = 0; ni < 4; ++ni) {
          float v = acc[ni][r];
          dst[ni * 16] = __float2bfloat16(v > 0.f ? v : 0.f);
        }
      } else {
        int token = perm[base + m0 + row];
        float p = prob[token];
        float* dst = Cf + (size_t)token * N + n0 + wc * 64 + lr;
#pragma unroll
        for (int ni = 0; ni < 4; ++ni) dst[ni * 16] = acc[ni][r] * p;
      }
    }
  }
}

extern "C" void kernel_launch(void* const* d_in, const int* in_sizes, int n_in,
                              void* d_out, int out_size, void* d_ws, size_t ws_size,
                              hipStream_t stream) {
  const float* X = (const float*)d_in[0];
  const float* Wr = (const float*)d_in[1];
  const float* W1 = (const float*)d_in[2];
  const float* W2 = (const float*)d_in[3];

  float* out_states = (float*)d_out;
  float* out_logits = out_states + (size_t)T_TOKENS * H_DIM;
  float* out_index = out_logits + (size_t)T_TOKENS * E_NUM;

  char* ws = (char*)d_ws;
  int* counts = (int*)(ws + 0);        // 8 ints
  int* offs = (int*)(ws + 64);         // 9 ints
  int* expert = (int*)(ws + 128);      // 2048 ints
  float* prob = (float*)(ws + 8320);   // 2048 f32
  int* perm = (int*)(ws + 16512);      // 2048 ints
  int* mse1 = (int*)(ws + 24704);      // 40 ints
  int* msm1 = (int*)(ws + 24896);      // 40 ints
  int* mse2 = (int*)(ws + 25088);      // 72 ints
  int* msm2 = (int*)(ws + 25408);      // 72 ints
  __hip_bfloat16* xg = (__hip_bfloat16*)(ws + 25728);      // 2048*768 bf16
  __hip_bfloat16* hbuf = (__hip_bfloat16*)(ws + 3171456);  // 2048*3072 bf16

  hipMemsetAsync(d_ws, 0, 64, stream);  // zero counts

  router_kernel<<<T_TOKENS / 4, 256, 0, stream>>>(X, Wr, out_logits, out_index, expert, prob, counts);
  scan_scatter_kernel<<<1, 1024, 0, stream>>>(counts, expert, offs, perm, mse1, msm1, mse2, msm2);
  gather_kernel<<<T_TOKENS / 4, 256, 0, stream>>>(X, perm, xg);

  // h = relu(xg @ W1[e]) : K=768, N=3072 -> 24 n-tiles x 40 slots = 960 blocks
  moe_gemm<1, H_DIM, F_DIM, 512, MSLOTS1><<<(F_DIM / 128) * MSLOTS1, 512, 0, stream>>>(
      xg, W1, hbuf, nullptr, offs, nullptr, nullptr, mse1, msm1);
  // y = (h @ W2[e]) * prob, scattered : K=3072, N=768 -> 6 x 72 = 432 blocks
  moe_gemm<0, F_DIM, H_DIM, 256, MSLOTS2><<<(H_DIM / 128) * MSLOTS2, 256, 0, stream>>>(
      hbuf, W2, nullptr, out_states, offs, perm, prob, mse2, msm2);
}

// Round 7
// 112.596 us; speedup vs baseline: 1.1661x; 1.0989x over previous
//
#include <hip/hip_runtime.h>
#include <hip/hip_bf16.h>

// Switch MoE (top-1), B=2 S=1024 H=768 F=3072 E=8 on MI355X.
// Outputs concat in d_out: next_states[2048*768] f32, router_logits[2048*8] f32,
// expert_index[2048] written as float values.

#define T_TOKENS 2048
#define H_DIM 768
#define F_DIM 3072
#define E_NUM 8
#define MSLOTS 40  // 64-row tiles: sum ceil(cnt/64) <= 32+7, padded to 40

typedef __attribute__((ext_vector_type(8))) short bf16x8;
typedef __attribute__((ext_vector_type(4))) float f32x4;

__device__ inline unsigned short f2bf(float f) {
  __hip_bfloat16 b = __float2bfloat16(f);
  return *reinterpret_cast<unsigned short*>(&b);
}
__device__ inline unsigned int pack2(float lo, float hi) {
  return (unsigned int)f2bf(lo) | ((unsigned int)f2bf(hi) << 16);
}

// ---------------- Router: one wave per token ----------------
__global__ void router_kernel(const float* __restrict__ X, const float* __restrict__ Wr,
                              float* __restrict__ logits, float* __restrict__ idx_out,
                              int* __restrict__ expert, float* __restrict__ prob,
                              int* __restrict__ counts) {
  int wave = threadIdx.x >> 6, lane = threadIdx.x & 63;
  int t = blockIdx.x * 4 + wave;
  if (t >= T_TOKENS) return;
  const float* x = X + (size_t)t * H_DIM;
  float acc[E_NUM];
#pragma unroll
  for (int e = 0; e < E_NUM; ++e) acc[e] = 0.f;
  int h0 = lane * 12;
#pragma unroll
  for (int j = 0; j < 12; ++j) {
    float xv = x[h0 + j];
    const float4* wr = reinterpret_cast<const float4*>(Wr + (size_t)(h0 + j) * E_NUM);
    float4 w0 = wr[0], w1 = wr[1];
    acc[0] += xv * w0.x; acc[1] += xv * w0.y; acc[2] += xv * w0.z; acc[3] += xv * w0.w;
    acc[4] += xv * w1.x; acc[5] += xv * w1.y; acc[6] += xv * w1.z; acc[7] += xv * w1.w;
  }
#pragma unroll
  for (int e = 0; e < E_NUM; ++e) {
#pragma unroll
    for (int s = 32; s > 0; s >>= 1) acc[e] += __shfl_down(acc[e], s);
  }
  if (lane == 0) {
    float m = acc[0]; int am = 0;
#pragma unroll
    for (int e = 1; e < E_NUM; ++e) {
      if (acc[e] > m) { m = acc[e]; am = e; }  // strict > == jnp.argmax first-occurrence
    }
    float sum = 0.f;
#pragma unroll
    for (int e = 0; e < E_NUM; ++e) sum += __expf(acc[e] - m);
    float p = 1.f / sum;
#pragma unroll
    for (int e = 0; e < E_NUM; ++e) logits[(size_t)t * E_NUM + e] = acc[e];
    idx_out[t] = (float)am;
    expert[t] = am;
    prob[t] = p;
    atomicAdd(&counts[am], 1);
  }
}

// ------- Fused scan + scatter + slot table (one block) -------
__global__ void scan_scatter_kernel(const int* __restrict__ counts,
                                    const int* __restrict__ expert,
                                    int* __restrict__ offs, int* __restrict__ perm,
                                    int* __restrict__ mse, int* __restrict__ msm0) {
  __shared__ int so[E_NUM + 1];
  __shared__ int cur[E_NUM];
  int tid = threadIdx.x;
  if (tid == 0) {
    int s = 0;
    for (int e = 0; e < E_NUM; ++e) { so[e] = s; s += counts[e]; }
    so[E_NUM] = s;
    int ns = 0;
    for (int e = 0; e < E_NUM; ++e)
      for (int m0 = 0; m0 < counts[e]; m0 += 64) { mse[ns] = e; msm0[ns] = m0; ++ns; }
    for (; ns < MSLOTS; ++ns) { mse[ns] = -1; msm0[ns] = 0; }
  }
  if (tid < E_NUM) cur[tid] = 0;
  __syncthreads();
  if (tid < E_NUM + 1) offs[tid] = so[tid];
  for (int i = tid; i < T_TOKENS; i += blockDim.x) {
    int e = expert[i];
    int pos = atomicAdd(&cur[e], 1);
    perm[so[e] + pos] = i;
  }
}

// ---------------- Gather X rows -> contiguous bf16 ----------------
__global__ void gather_kernel(const float* __restrict__ X, const int* __restrict__ perm,
                              __hip_bfloat16* __restrict__ xg) {
  int wave = threadIdx.x >> 6, lane = threadIdx.x & 63;
  int g = blockIdx.x * 4 + wave;
  if (g >= T_TOKENS) return;
  int token = perm[g];
  const float4* src = reinterpret_cast<const float4*>(X + (size_t)token * H_DIM + lane * 12);
  __hip_bfloat16* dst = xg + (size_t)g * H_DIM + lane * 12;
#pragma unroll
  for (int i = 0; i < 3; ++i) {
    float4 v = src[i];
    ushort4 u;
    u.x = f2bf(v.x); u.y = f2bf(v.y); u.z = f2bf(v.z); u.w = f2bf(v.w);
    *reinterpret_cast<ushort4*>(dst + i * 4) = u;
  }
}

// ---------------- Grouped GEMM, depth-2, 3 blocks/CU ----------------
// C[m,n] (+k-chunk) = sum_{k in chunk} A[m,k] * W[e][k,n].
// BM=64, BN=128, BK=64, chunk=768 (nt=12). T=256: 4 waves as 2m x 2n,
// wavetile 32x64 (acc 2x4 frags). Double-buffered 48KB LDS -> 3 blocks/CU.
// Step t: {ds_read+MFMA buf[t&1]} {auto-vmcnt; pack+ds_write tile t+1 ->
// buf[(t+1)&1]} {issue loads tile t+2} {lgkm(0); barrier}. Branch-free body.
// LDS rows 128B = 8 x 16B slots. A hash: slot^(row&7). B hash:
// slot^(row&7)^((row>>3)&7). All write/read patterns uniform 8 lanes/slot.
// MODE 1: relu -> bf16 Cbf. MODE 0: raw f32 partial -> Cf (split-K).
template <int MODE, int KT, int N, int KS>
__global__ __launch_bounds__(256, 3) void moe_gemm(
    const __hip_bfloat16* __restrict__ A, const float* __restrict__ Wt,
    __hip_bfloat16* __restrict__ Cbf, float* __restrict__ Cf,
    const int* __restrict__ offs, const int* __restrict__ mse,
    const int* __restrict__ msm0) {
  constexpr int ABUF = 64 * 128;           // 8 KB
  constexpr int BUFSZ = ABUF + 128 * 128;  // 24 KB
  constexpr int nt = 12;                   // 768 / 64
  __shared__ __align__(16) char lds[2 * BUFSZ];

  // ---- work decode with XCD-chunk swizzle (grid multiple of 8) ----
  const int nw = gridDim.x;
  const int cpx = nw >> 3;
  const int d = blockIdx.x;
  const int w = (d & 7) * cpx + (d >> 3);
  const int slot = w % MSLOTS;
  const int r_ = w / MSLOTS;
  const int ks = r_ % KS;
  const int nt_i = r_ / KS;
  const int e = mse[slot];
  if (e < 0) return;
  const int base = offs[e], cnt = offs[e + 1] - base;
  const int m0 = msm0[slot];
  const int rows = min(64, cnt - m0);
  const int n0 = nt_i * 128;
  const int koff = ks * 768;

  const int tid = threadIdx.x;
  const int lane = tid & 63, wv = tid >> 6;
  const int wr = wv >> 1, wc = wv & 1;     // 2m x 2n waves
  const int lr = lane & 15, lg = lane >> 4;

  // ---- A staging: thread -> (row, 32B = 2 slots) ----
  const int arow = tid >> 2, apair = (tid & 3) * 2;
  const __hip_bfloat16* Ap =
      A + (size_t)(base + m0 + min(arow, rows - 1)) * KT + koff + apair * 8;
  const int a_woff0 = arow * 128 + ((apair ^ (arow & 7)) << 4);
  const int a_woff1 = arow * 128 + (((apair + 1) ^ (arow & 7)) << 4);

  // ---- B staging: thread -> (4 n-cols, 8 k-rows), float4 loads ----
  const int n4 = (tid & 31) * 4;
  const int k8 = (tid >> 5) * 8;
  const float* Bp = Wt + (size_t)e * KT * N + (size_t)(koff + k8) * N + n0 + n4;
  int b_woff[4];
#pragma unroll
  for (int cc = 0; cc < 4; ++cc) {
    int row_ = n4 + cc;
    int h_ = (row_ & 7) ^ ((row_ >> 3) & 7);
    b_woff[cc] = ABUF + row_ * 128 + (((tid >> 5) ^ h_) << 4);
  }

  // ---- fragment LDS offsets ----
  int aof[2][2], bof[2][4];
#pragma unroll
  for (int ks2 = 0; ks2 < 2; ++ks2) {
#pragma unroll
    for (int mi = 0; mi < 2; ++mi) {
      int ar = wr * 32 + mi * 16 + lr;
      aof[ks2][mi] = ar * 128 + (((ks2 * 4 + lg) ^ (ar & 7)) << 4);
    }
#pragma unroll
    for (int ni = 0; ni < 4; ++ni) {
      int br = wc * 64 + ni * 16 + lr;
      bof[ks2][ni] = ABUF + br * 128 +
                     (((ks2 * 4 + lg) ^ (br & 7) ^ ((br >> 3) & 7)) << 4);
    }
  }

  f32x4 acc[2][4];
#pragma unroll
  for (int i = 0; i < 2; ++i)
#pragma unroll
    for (int j = 0; j < 4; ++j) acc[i][j] = (f32x4){0.f, 0.f, 0.f, 0.f};

  int4 aq0, aq1;
  f32x4 bq[8];

#define LOADT(TT) {                                                             \
    aq0 = *reinterpret_cast<const int4*>(Ap + (TT) * 64);                       \
    aq1 = *reinterpret_cast<const int4*>(Ap + (TT) * 64 + 8);                   \
    _Pragma("unroll")                                                           \
    for (int r = 0; r < 8; ++r)                                                 \
      bq[r] = *reinterpret_cast<const f32x4*>(Bp + (size_t)((TT) * 64 + r) * N);\
  }

#define WRITET(WB) {                                                            \
    char* wb_ = (WB);                                                           \
    *reinterpret_cast<int4*>(wb_ + a_woff0) = aq0;                              \
    *reinterpret_cast<int4*>(wb_ + a_woff1) = aq1;                              \
    _Pragma("unroll")                                                           \
    for (int cc = 0; cc < 4; ++cc) {                                            \
      int4 u_;                                                                  \
      u_.x = (int)pack2(bq[0][cc], bq[1][cc]);                                  \
      u_.y = (int)pack2(bq[2][cc], bq[3][cc]);                                  \
      u_.z = (int)pack2(bq[4][cc], bq[5][cc]);                                  \
      u_.w = (int)pack2(bq[6][cc], bq[7][cc]);                                  \
      *reinterpret_cast<int4*>(wb_ + b_woff[cc]) = u_;                          \
    }                                                                           \
  }

#define MFMA_STEP(RB) {                                                         \
    const char* rb_ = (RB);                                                     \
    _Pragma("unroll")                                                           \
    for (int ks2 = 0; ks2 < 2; ++ks2) {                                         \
      bf16x8 av0 = *reinterpret_cast<const bf16x8*>(rb_ + aof[ks2][0]);         \
      bf16x8 av1 = *reinterpret_cast<const bf16x8*>(rb_ + aof[ks2][1]);         \
      _Pragma("unroll")                                                         \
      for (int ni = 0; ni < 4; ++ni) {                                          \
        bf16x8 bv = *reinterpret_cast<const bf16x8*>(rb_ + bof[ks2][ni]);       \
        acc[0][ni] = __builtin_amdgcn_mfma_f32_16x16x32_bf16(av0, bv, acc[0][ni], 0, 0, 0); \
        acc[1][ni] = __builtin_amdgcn_mfma_f32_16x16x32_bf16(av1, bv, acc[1][ni], 0, 0, 0); \
      }                                                                         \
    }                                                                           \
  }

#define SYNCB() {                                                               \
    asm volatile("s_waitcnt lgkmcnt(0)" ::: "memory");                          \
    __builtin_amdgcn_s_barrier();                                               \
    __builtin_amdgcn_sched_barrier(0);                                          \
  }

  char* const buf0 = lds;
  char* const buf1 = lds + BUFSZ;

  // prologue: tile0 -> buf0; tile1 loads in flight
  LOADT(0);
  WRITET(buf0);   // compiler inserts vmcnt before first ds_write
  LOADT(1);
  SYNCB();

  // branch-free main body: steps 0..9 (reads buf t&1, writes tile t+1, loads t+2)
#pragma unroll 1
  for (int t0 = 0; t0 < 10; t0 += 2) {
    MFMA_STEP(buf0); WRITET(buf1); LOADT(t0 + 2); SYNCB();
    MFMA_STEP(buf1); WRITET(buf0); LOADT(t0 + 3); SYNCB();
  }
  // step 10: write tile 11, no more loads
  MFMA_STEP(buf0); WRITET(buf1); SYNCB();
  // step 11: compute only
  MFMA_STEP(buf1);
#undef LOADT
#undef WRITET
#undef MFMA_STEP
#undef SYNCB

  // ---- epilogue: C/D frag row=(lane>>4)*4+reg, col=lane&15 ----
#pragma unroll
  for (int mi = 0; mi < 2; ++mi) {
#pragma unroll
    for (int r = 0; r < 4; ++r) {
      int row = wr * 32 + mi * 16 + lg * 4 + r;
      if (row < rows) {
        if (MODE) {
          __hip_bfloat16* dst = Cbf + (size_t)(base + m0 + row) * N + n0 + wc * 64 + lr;
#pragma unroll
          for (int ni = 0; ni < 4; ++ni) {
            float v = acc[mi][ni][r];
            dst[ni * 16] = __float2bfloat16(v > 0.f ? v : 0.f);
          }
        } else {
          float* dst = Cf + ((size_t)ks * T_TOKENS + base + m0 + row) * N + n0 + wc * 64 + lr;
#pragma unroll
          for (int ni = 0; ni < 4; ++ni) dst[ni * 16] = acc[mi][ni][r];
        }
      }
    }
  }
}

// ---------------- Split-K reduce: sum 4 partials, scale by prob, scatter ----------------
__global__ void reduce_kernel(const float* __restrict__ pc, const int* __restrict__ perm,
                              const float* __restrict__ prob, float* __restrict__ out) {
  int idx = blockIdx.x * 256 + threadIdx.x;      // 2048 * 192
  int g = idx / (H_DIM / 4);
  int c4 = (idx - g * (H_DIM / 4)) * 4;
  int token = perm[g];
  float p = prob[token];
  f32x4 s = (f32x4){0.f, 0.f, 0.f, 0.f};
#pragma unroll
  for (int ks = 0; ks < 4; ++ks)
    s += *reinterpret_cast<const f32x4*>(pc + ((size_t)ks * T_TOKENS + g) * H_DIM + c4);
  s *= p;
  *reinterpret_cast<f32x4*>(out + (size_t)token * H_DIM + c4) = s;
}

extern "C" void kernel_launch(void* const* d_in, const int* in_sizes, int n_in,
                              void* d_out, int out_size, void* d_ws, size_t ws_size,
                              hipStream_t stream) {
  const float* X = (const float*)d_in[0];
  const float* Wr = (const float*)d_in[1];
  const float* W1 = (const float*)d_in[2];
  const float* W2 = (const float*)d_in[3];

  float* out_states = (float*)d_out;
  float* out_logits = out_states + (size_t)T_TOKENS * H_DIM;
  float* out_index = out_logits + (size_t)T_TOKENS * E_NUM;

  char* ws = (char*)d_ws;
  int* counts = (int*)(ws + 0);        // 8 ints
  int* offs = (int*)(ws + 64);         // 9 ints
  int* expert = (int*)(ws + 128);      // 2048 ints
  float* prob = (float*)(ws + 8320);   // 2048 f32
  int* perm = (int*)(ws + 16512);      // 2048 ints
  int* mse = (int*)(ws + 24704);       // 40 ints
  int* msm0 = (int*)(ws + 24896);      // 40 ints
  __hip_bfloat16* xg = (__hip_bfloat16*)(ws + 25088);      // 2048*768 bf16
  __hip_bfloat16* hbuf = (__hip_bfloat16*)(ws + 3171456);  // 2048*3072 bf16
  float* pc = (float*)(ws + 15754368);                     // 4*2048*768 f32 (25.2 MB)

  hipMemsetAsync(d_ws, 0, 64, stream);  // zero counts

  router_kernel<<<T_TOKENS / 4, 256, 0, stream>>>(X, Wr, out_logits, out_index, expert, prob, counts);
  scan_scatter_kernel<<<1, 1024, 0, stream>>>(counts, expert, offs, perm, mse, msm0);
  gather_kernel<<<T_TOKENS / 4, 256, 0, stream>>>(X, perm, xg);

  // h = relu(xg @ W1[e]) : K=768 (1 chunk), N=3072 -> 24 x 40 = 960 blocks
  moe_gemm<1, H_DIM, F_DIM, 1><<<(F_DIM / 128) * MSLOTS, 256, 0, stream>>>(
      xg, W1, hbuf, nullptr, offs, mse, msm0);
  // partial y_ks = h @ W2[e][ks-chunk] : 4 chunks of 768 -> 6 x 4 x 40 = 960 blocks
  moe_gemm<0, F_DIM, H_DIM, 4><<<(H_DIM / 128) * 4 * MSLOTS, 256, 0, stream>>>(
      hbuf, W2, nullptr, pc, offs, mse, msm0);
  // out[token] = prob * sum_ks pc[ks][g]
  reduce_kernel<<<(T_TOKENS * (H_DIM / 4)) / 256, 256, 0, stream>>>(pc, perm, prob, out_states);
}